// Round 3
// baseline (1931.938 us; speedup 1.0000x reference)
//
#include <hip/hip_runtime.h>
#include <hip/hip_bf16.h>
#include <math.h>

#define HC 768   // 3F concat width
#define DPB 8    // dsts owned per block in edge kernel

// order-preserving float->uint encoding for max
__device__ __forceinline__ unsigned enc_f(float f) {
    unsigned u = __float_as_uint(f);
    return (u & 0x80000000u) ? ~u : (u | 0x80000000u);
}
__device__ __forceinline__ float dec_f(unsigned e) {
    unsigned u = (e & 0x80000000u) ? (e & 0x7FFFFFFFu) : ~e;
    return __uint_as_float(u);
}
#define ENC_NEG_INF 0x007FFFFFu  // enc(-inf)

// ---------------- precompute: temb (Fourier+silu), h0, hcat, invstd ----------
__global__ void precompute_kernel(const float* __restrict__ x,
                                  const float* __restrict__ t,
                                  const float* __restrict__ emb,
                                  const float* __restrict__ enc_W,
                                  const float* __restrict__ enc_b,
                                  const float* __restrict__ fw,
                                  const float* __restrict__ te_W,
                                  const float* __restrict__ te_b,
                                  float* __restrict__ hcat,
                                  float* __restrict__ invstd,
                                  int N) {
    __shared__ float ti[8][256];
    __shared__ float tv[8];
    const int n0 = blockIdx.x * 8;
    const int tid = threadIdx.x;

    if (tid < 8) {
        int n = n0 + tid;
        float tt = (n < N) ? t[n] : 1.0f;
        tv[tid] = tt;
        const float ln_s = 3.2188758248682006f; // ln(25)
        float p = expf(2.0f * tt * ln_s);       // SIGMA^(2t)
        float sd = sqrtf((p - 1.0f) / (2.0f * ln_s));
        if (n < N) invstd[n] = 1.0f / (sd + 1e-7f);
    }
    __syncthreads();

    const float TWO_PI = 6.283185307179586f;
    for (int p = tid; p < 8 * 128; p += 256) {
        int n = p >> 7, j = p & 127;
        float pr = tv[n] * fw[j] * TWO_PI;
        ti[n][j]       = sinf(pr);
        ti[n][j + 128] = cosf(pr);
    }
    __syncthreads();

    const int j = tid;
    float acc[8];
#pragma unroll
    for (int n = 0; n < 8; ++n) acc[n] = 0.f;
    for (int k = 0; k < 256; ++k) {
        float w = te_W[k * 256 + j];
#pragma unroll
        for (int n = 0; n < 8; ++n) acc[n] += ti[n][k] * w;
    }
    float bj  = te_b[j];
    float ew0 = enc_W[0 * 256 + j], ew1 = enc_W[1 * 256 + j], ew2 = enc_W[2 * 256 + j];
    float ebj = enc_b[j];
    for (int n = 0; n < 8; ++n) {
        int node = n0 + n;
        if (node >= N) break;
        float v = acc[n] + bj;
        float temb = v / (1.0f + expf(-v));   // silu
        float h0 = x[node * 3 + 0] * ew0 + x[node * 3 + 1] * ew1 +
                   x[node * 3 + 2] * ew2 + ebj;
        hcat[node * HC + j]       = h0;
        hcat[node * HC + 256 + j] = temb;
        hcat[node * HC + 512 + j] = emb[node * 256 + j];
    }
}

// ------------- Wcat = [A - B | B] from W1 (1536x256) -> (768x512) ------------
__global__ void prep_w_kernel(const float* __restrict__ W1, float* __restrict__ Wcat) {
    int idx = blockIdx.x * 256 + threadIdx.x;
    if (idx >= 768 * 512) return;
    int k = idx >> 9;
    int jj = idx & 511;
    float v;
    if (jj < 256) v = W1[k * 256 + jj] - W1[(k + 768) * 256 + jj];
    else          v = W1[(k + 768) * 256 + (jj - 256)];
    Wcat[idx] = v;
}

// ------------- RQ (N x 512) = hcat (N x 768) @ Wcat (768x512); R += b1 -------
__global__ void node_gemm_kernel(const float* __restrict__ A,
                                 const float* __restrict__ W,
                                 const float* __restrict__ b1,
                                 float* __restrict__ C,
                                 int M) {
    __shared__ float a_t[8][64];
    __shared__ float w_t[8][64];
    const int row0 = blockIdx.x * 64;
    const int col0 = blockIdx.y * 64;
    const int tid = threadIdx.x;
    const int tx = tid & 15, ty = tid >> 4;
    float acc[4][4];
#pragma unroll
    for (int i = 0; i < 4; ++i)
#pragma unroll
        for (int j = 0; j < 4; ++j) acc[i][j] = 0.f;

    for (int k0 = 0; k0 < 768; k0 += 8) {
        __syncthreads();
#pragma unroll
        for (int i = 0; i < 2; ++i) {
            int idx = tid + i * 256;
            int kk = idx >> 6, r = idx & 63;
            int row = row0 + r;
            a_t[kk][r] = (row < M) ? A[(size_t)row * HC + k0 + kk] : 0.f;
            w_t[kk][r] = W[(k0 + kk) * 512 + col0 + r];
        }
        __syncthreads();
#pragma unroll
        for (int kk = 0; kk < 8; ++kk) {
            const float4 av = *reinterpret_cast<const float4*>(&a_t[kk][ty * 4]);
            const float4 wv = *reinterpret_cast<const float4*>(&w_t[kk][tx * 4]);
            float aa[4] = {av.x, av.y, av.z, av.w};
            float ww[4] = {wv.x, wv.y, wv.z, wv.w};
#pragma unroll
            for (int i = 0; i < 4; ++i)
#pragma unroll
                for (int j = 0; j < 4; ++j)
                    acc[i][j] = fmaf(aa[i], ww[j], acc[i][j]);
        }
    }
#pragma unroll
    for (int i = 0; i < 4; ++i) {
        int row = row0 + ty * 4 + i;
        if (row >= M) continue;
#pragma unroll
        for (int j = 0; j < 4; ++j) {
            int col = col0 + tx * 4 + j;
            float v = acc[i][j] + (col < 256 ? b1[col] : 0.f);
            C[(size_t)row * 512 + col] = v;
        }
    }
}

// ---------------- edge sort by dst: zero / hist / scan / scatter -------------
__global__ void zero_u32_kernel(unsigned* __restrict__ p, int count) {
    int idx = blockIdx.x * 256 + threadIdx.x;
    if (idx < count) p[idx] = 0u;
}
__global__ void hist_kernel(const int* __restrict__ dst, unsigned* __restrict__ cnt, int E) {
    int e = blockIdx.x * 256 + threadIdx.x;
    if (e < E) atomicAdd(&cnt[dst[e]], 1u);
}
__global__ void scan_kernel(const unsigned* __restrict__ cnt,
                            int* __restrict__ row_start, int N) {
    __shared__ unsigned buf[1024];
    __shared__ unsigned carry;
    const int tid = threadIdx.x;
    if (tid == 0) carry = 0u;
    __syncthreads();
    for (int base = 0; base < N; base += 1024) {
        int i = base + tid;
        unsigned v = (i < N) ? cnt[i] : 0u;
        buf[tid] = v;
        __syncthreads();
#pragma unroll
        for (int off = 1; off < 1024; off <<= 1) {
            unsigned add = (tid >= off) ? buf[tid - off] : 0u;
            __syncthreads();
            buf[tid] += add;
            __syncthreads();
        }
        if (i < N) row_start[i] = (int)(carry + buf[tid] - v);  // exclusive
        __syncthreads();
        if (tid == 0) carry += buf[1023];
        __syncthreads();
    }
    if (tid == 0) row_start[N] = (int)carry;  // == E
}
__global__ void scatter_kernel(const int* __restrict__ src, const int* __restrict__ dst,
                               const int* __restrict__ row_start,
                               unsigned* __restrict__ wcnt,
                               int* __restrict__ es, int* __restrict__ ed, int E) {
    int e = blockIdx.x * 256 + threadIdx.x;
    if (e >= E) return;
    int d = dst[e];
    int pos = row_start[d] + (int)atomicAdd(&wcnt[d], 1u);
    es[pos] = src[e];
    ed[pos] = d;
}

// ---- edges (layers 1,2), dst-OWNER blocks: relu(R[dst]+Q[src]) @ W2 + b2 ----
// Each block owns DPB consecutive dsts (edges sorted by dst). Segment max is
// kept in LDS (block-local atomics only); final = relu(max+b2) stored straight
// into hcat with plain stores. No global atomics, no seg buffer.
__global__ __launch_bounds__(256, 4)
void edge_gemm_owner_kernel(const float* __restrict__ RQ,
                            const int* __restrict__ es,
                            const int* __restrict__ ed,
                            const int* __restrict__ row_start,  // N+1
                            const float* __restrict__ W2,
                            const float* __restrict__ b2,
                            float* __restrict__ hcat,
                            int N, int E) {
    __shared__ float a_t[8][64];      // [k][edge]
    __shared__ float w_t[8][256];     // [k][col]
    __shared__ unsigned lseg[DPB][256];
    __shared__ int ss[64], sdl[64];   // src node, local dst idx (-1 = pad)
    const int d0 = blockIdx.x * DPB;
    const int tid = threadIdx.x;
    const int tx = tid & 31;          // cols tx*4..+3 and 128+tx*4..+3
    const int ty = tid >> 5;          // edges ty*8..+7

    for (int i = tid; i < DPB * 256; i += 256)
        ((unsigned*)lseg)[i] = ENC_NEG_INF;

    const int eBeg = row_start[d0];
    const int eEnd = row_start[min(d0 + DPB, N)];

    for (int c0 = eBeg; c0 < eEnd; c0 += 64) {
        __syncthreads();   // prior chunk done reading ss/sdl
        if (tid < 64) {
            int e = c0 + tid;
            if (e < eEnd) { ss[tid] = es[e]; sdl[tid] = ed[e] - d0; }
            else          { ss[tid] = 0;     sdl[tid] = -1; }
        }
        __syncthreads();

        float acc[8][8];
#pragma unroll
        for (int i = 0; i < 8; ++i)
#pragma unroll
            for (int j = 0; j < 8; ++j) acc[i][j] = 0.f;

        for (int k0 = 0; k0 < 256; k0 += 8) {
            __syncthreads();
            if (tid < 128) {
                // A staging: 64 edges x 8 k, gather + relu, float4 along k
                int e = tid & 63;
                int kq = tid >> 6;    // 0/1 -> k sub-chunk of 4
                int dl = sdl[e];
                int rd = (dl >= 0) ? (d0 + dl) : d0;
                int rs = ss[e];
                float4 dv = *reinterpret_cast<const float4*>(&RQ[(size_t)rd * 512 + k0 + kq * 4]);
                float4 sv = *reinterpret_cast<const float4*>(&RQ[(size_t)rs * 512 + 256 + k0 + kq * 4]);
                a_t[kq * 4 + 0][e] = fmaxf(dv.x + sv.x, 0.f);
                a_t[kq * 4 + 1][e] = fmaxf(dv.y + sv.y, 0.f);
                a_t[kq * 4 + 2][e] = fmaxf(dv.z + sv.z, 0.f);
                a_t[kq * 4 + 3][e] = fmaxf(dv.w + sv.w, 0.f);
            } else {
                // W staging: 8 k x 256 cols = 512 float4s, 4 per thread
                int t2 = tid - 128;
#pragma unroll
                for (int q = 0; q < 4; ++q) {
                    int id = t2 + 128 * q;
                    int kk = id >> 6, c = id & 63;
                    float4 wv = *reinterpret_cast<const float4*>(&W2[(size_t)(k0 + kk) * 256 + c * 4]);
                    *reinterpret_cast<float4*>(&w_t[kk][c * 4]) = wv;
                }
            }
            __syncthreads();
#pragma unroll
            for (int kk = 0; kk < 8; ++kk) {
                const float4 a0 = *reinterpret_cast<const float4*>(&a_t[kk][ty * 8]);
                const float4 a1 = *reinterpret_cast<const float4*>(&a_t[kk][ty * 8 + 4]);
                const float4 w0 = *reinterpret_cast<const float4*>(&w_t[kk][tx * 4]);
                const float4 w1 = *reinterpret_cast<const float4*>(&w_t[kk][128 + tx * 4]);
                float aa[8] = {a0.x, a0.y, a0.z, a0.w, a1.x, a1.y, a1.z, a1.w};
                float ww[8] = {w0.x, w0.y, w0.z, w0.w, w1.x, w1.y, w1.z, w1.w};
#pragma unroll
                for (int i = 0; i < 8; ++i)
#pragma unroll
                    for (int j = 0; j < 8; ++j)
                        acc[i][j] = fmaf(aa[i], ww[j], acc[i][j]);
            }
        }

        // segmented max epilogue -> LDS atomics (block-local)
        float m[8];
#pragma unroll
        for (int j = 0; j < 8; ++j) m[j] = -INFINITY;
        const int r0 = ty * 8;
#pragma unroll
        for (int i = 0; i < 8; ++i) {
            int dl = sdl[r0 + i];
            if (dl < 0) break;   // padding is suffix-only
#pragma unroll
            for (int j = 0; j < 8; ++j) m[j] = fmaxf(m[j], acc[i][j]);
            bool flush = (i == 7) || (sdl[r0 + i + 1] != dl);
            if (flush) {
#pragma unroll
                for (int j = 0; j < 8; ++j) {
                    int col = (j < 4) ? (tx * 4 + j) : (128 + tx * 4 + (j - 4));
                    atomicMax(&lseg[dl][col], enc_f(m[j]));
                    m[j] = -INFINITY;
                }
            }
        }
    }
    __syncthreads();

    // write relu(max + b2) (0 for empty segments) straight into hcat
    for (int i = tid; i < DPB * 256; i += 256) {
        int dl = i >> 8, col = i & 255;
        int d = d0 + dl;
        if (d >= N) continue;
        float f = dec_f(lseg[dl][col]);
        float v = isfinite(f) ? fmaxf(f + b2[col], 0.f) : 0.f;
        hcat[(size_t)d * HC + col] = v;
    }
}

// ---- layer 3 edges: out width 3, one wave per edge --------------------------
__global__ void edge3_kernel(const float* __restrict__ RQ,
                             const int* __restrict__ src,
                             const int* __restrict__ dst,
                             const float* __restrict__ W2,   // 256x3
                             const float* __restrict__ b2,   // 3
                             unsigned* __restrict__ seg3,
                             int E) {
    int wave = blockIdx.x * 4 + (threadIdx.x >> 6);
    int lane = threadIdx.x & 63;
    if (wave >= E) return;
    int s = src[wave], d = dst[wave];
    float p0 = 0.f, p1 = 0.f, p2 = 0.f;
    for (int k = lane; k < 256; k += 64) {
        float a = fmaxf(RQ[(size_t)d * 512 + k] + RQ[(size_t)s * 512 + 256 + k], 0.f);
        p0 += a * W2[k * 3 + 0];
        p1 += a * W2[k * 3 + 1];
        p2 += a * W2[k * 3 + 2];
    }
#pragma unroll
    for (int off = 32; off > 0; off >>= 1) {
        p0 += __shfl_xor(p0, off);
        p1 += __shfl_xor(p1, off);
        p2 += __shfl_xor(p2, off);
    }
    if (lane == 0) {
        atomicMax(&seg3[(size_t)d * 3 + 0], enc_f(p0 + b2[0]));
        atomicMax(&seg3[(size_t)d * 3 + 1], enc_f(p1 + b2[1]));
        atomicMax(&seg3[(size_t)d * 3 + 2], enc_f(p2 + b2[2]));
    }
}

// ---------------- misc ------------------------------------------------------
__global__ void seg_init_kernel(unsigned* __restrict__ seg, int count) {
    int idx = blockIdx.x * 256 + threadIdx.x;
    if (idx < count) seg[idx] = ENC_NEG_INF;
}
__global__ void finalize3_kernel(const unsigned* __restrict__ seg3,
                                 const float* __restrict__ invstd,
                                 float* __restrict__ out, int N) {
    int idx = blockIdx.x * 256 + threadIdx.x;
    if (idx >= N * 3) return;
    int n = idx / 3;
    float f = dec_f(seg3[idx]);
    if (!isfinite(f)) f = 0.f;
    out[idx] = f * invstd[n];
}

extern "C" void kernel_launch(void* const* d_in, const int* in_sizes, int n_in,
                              void* d_out, int out_size, void* d_ws, size_t ws_size,
                              hipStream_t stream) {
    const float* x     = (const float*)d_in[0];
    const int*   ei    = (const int*)d_in[1];
    const float* t     = (const float*)d_in[2];
    const float* emb   = (const float*)d_in[3];
    const float* enc_W = (const float*)d_in[4];
    const float* enc_b = (const float*)d_in[5];
    const float* fw    = (const float*)d_in[6];
    const float* te_W  = (const float*)d_in[7];
    const float* te_b  = (const float*)d_in[8];
    const float* W1[3] = {(const float*)d_in[9],  (const float*)d_in[13], (const float*)d_in[17]};
    const float* b1[3] = {(const float*)d_in[10], (const float*)d_in[14], (const float*)d_in[18]};
    const float* W2[3] = {(const float*)d_in[11], (const float*)d_in[15], (const float*)d_in[19]};
    const float* b2[3] = {(const float*)d_in[12], (const float*)d_in[16], (const float*)d_in[20]};

    const int N = in_sizes[2];      // t is (N,1)
    const int E = in_sizes[1] / 2;  // edge_index is (2,E)
    const int* src = ei;
    const int* dst = ei + E;

    char* ws = (char*)d_ws;
    float*    hcat      = (float*)ws;    ws += (size_t)N * 768 * 4;
    float*    RQ        = (float*)ws;    ws += (size_t)N * 512 * 4;
    float*    Wcat      = (float*)ws;    ws += (size_t)768 * 512 * 4;
    unsigned* seg       = (unsigned*)ws; ws += (size_t)N * 256 * 4;
    float*    invstd    = (float*)ws;    ws += (size_t)N * 4;
    int*      es        = (int*)ws;      ws += (size_t)E * 4;
    int*      ed        = (int*)ws;      ws += (size_t)E * 4;
    unsigned* cnt       = (unsigned*)ws; ws += (size_t)N * 4;
    unsigned* wcnt      = (unsigned*)ws; ws += (size_t)N * 4;
    int*      row_start = (int*)ws;      ws += (size_t)(N + 1) * 4;

    // ---- sort edges by dst (counting sort) ----
    zero_u32_kernel<<<(2 * N + 255) / 256, 256, 0, stream>>>(cnt, 2 * N); // cnt+wcnt adjacent
    hist_kernel<<<(E + 255) / 256, 256, 0, stream>>>(dst, cnt, E);
    scan_kernel<<<1, 1024, 0, stream>>>(cnt, row_start, N);
    scatter_kernel<<<(E + 255) / 256, 256, 0, stream>>>(src, dst, row_start, wcnt, es, ed, E);

    precompute_kernel<<<(N + 7) / 8, 256, 0, stream>>>(
        x, t, emb, enc_W, enc_b, fw, te_W, te_b, hcat, invstd, N);

    for (int l = 0; l < 3; ++l) {
        prep_w_kernel<<<(768 * 512 + 255) / 256, 256, 0, stream>>>(W1[l], Wcat);
        dim3 gn((N + 63) / 64, 8);
        node_gemm_kernel<<<gn, 256, 0, stream>>>(hcat, Wcat, b1[l], RQ, N);
        if (l < 2) {
            edge_gemm_owner_kernel<<<(N + DPB - 1) / DPB, 256, 0, stream>>>(
                RQ, es, ed, row_start, W2[l], b2[l], hcat, N, E);
        } else {
            seg_init_kernel<<<(N * 3 + 255) / 256, 256, 0, stream>>>(seg, N * 3);
            edge3_kernel<<<(E + 3) / 4, 256, 0, stream>>>(RQ, es, ed, W2[l], b2[l], seg, E);
            finalize3_kernel<<<(N * 3 + 255) / 256, 256, 0, stream>>>(seg, invstd, (float*)d_out, N);
        }
    }
}

// Round 4
// 1067.324 us; speedup vs baseline: 1.8101x; 1.8101x over previous
//
#include <hip/hip_runtime.h>
#include <hip/hip_bf16.h>
#include <math.h>

#define HC 768   // 3F concat width (bf16 elements)
#define DPB 16   // dsts owned per block in edge kernel

typedef __attribute__((ext_vector_type(8))) short bf16x8;  // 8 bf16 (4 VGPRs)
typedef __attribute__((ext_vector_type(4))) float f32x4;   // MFMA accumulator

__device__ __forceinline__ float bf2f(unsigned short h) {
    return __uint_as_float(((unsigned)h) << 16);
}
__device__ __forceinline__ unsigned short f2bf(float f) {   // round-to-nearest-even
    unsigned u = __float_as_uint(f);
    return (unsigned short)((u + 0x7fffu + ((u >> 16) & 1u)) >> 16);
}

// order-preserving float->uint encoding for max
__device__ __forceinline__ unsigned enc_f(float f) {
    unsigned u = __float_as_uint(f);
    return (u & 0x80000000u) ? ~u : (u | 0x80000000u);
}
__device__ __forceinline__ float dec_f(unsigned e) {
    unsigned u = (e & 0x80000000u) ? (e & 0x7FFFFFFFu) : ~e;
    return __uint_as_float(u);
}
#define ENC_NEG_INF 0x007FFFFFu  // enc(-inf)

// ---------------- precompute: temb (Fourier+silu), h0, hcat(bf16), invstd ----
__global__ void precompute_kernel(const float* __restrict__ x,
                                  const float* __restrict__ t,
                                  const float* __restrict__ emb,
                                  const float* __restrict__ enc_W,
                                  const float* __restrict__ enc_b,
                                  const float* __restrict__ fw,
                                  const float* __restrict__ te_W,
                                  const float* __restrict__ te_b,
                                  unsigned short* __restrict__ hcat,
                                  float* __restrict__ invstd,
                                  int N) {
    __shared__ float ti[8][256];
    __shared__ float tv[8];
    const int n0 = blockIdx.x * 8;
    const int tid = threadIdx.x;

    if (tid < 8) {
        int n = n0 + tid;
        float tt = (n < N) ? t[n] : 1.0f;
        tv[tid] = tt;
        const float ln_s = 3.2188758248682006f; // ln(25)
        float p = expf(2.0f * tt * ln_s);       // SIGMA^(2t)
        float sd = sqrtf((p - 1.0f) / (2.0f * ln_s));
        if (n < N) invstd[n] = 1.0f / (sd + 1e-7f);
    }
    __syncthreads();

    const float TWO_PI = 6.283185307179586f;
    for (int p = tid; p < 8 * 128; p += 256) {
        int n = p >> 7, j = p & 127;
        float pr = tv[n] * fw[j] * TWO_PI;
        ti[n][j]       = sinf(pr);
        ti[n][j + 128] = cosf(pr);
    }
    __syncthreads();

    const int j = tid;
    float acc[8];
#pragma unroll
    for (int n = 0; n < 8; ++n) acc[n] = 0.f;
    for (int k = 0; k < 256; ++k) {
        float w = te_W[k * 256 + j];
#pragma unroll
        for (int n = 0; n < 8; ++n) acc[n] += ti[n][k] * w;
    }
    float bj  = te_b[j];
    float ew0 = enc_W[0 * 256 + j], ew1 = enc_W[1 * 256 + j], ew2 = enc_W[2 * 256 + j];
    float ebj = enc_b[j];
    for (int n = 0; n < 8; ++n) {
        int node = n0 + n;
        if (node >= N) break;
        float v = acc[n] + bj;
        float temb = v / (1.0f + expf(-v));   // silu
        float h0 = x[node * 3 + 0] * ew0 + x[node * 3 + 1] * ew1 +
                   x[node * 3 + 2] * ew2 + ebj;
        hcat[(size_t)node * HC + j]       = f2bf(h0);
        hcat[(size_t)node * HC + 256 + j] = f2bf(temb);
        hcat[(size_t)node * HC + 512 + j] = f2bf(emb[node * 256 + j]);
    }
}

// ---- WcatT[n][k] bf16 (512x768): n<256 -> W1_top-W1_bot col n; else W1_bot --
__global__ void prep_wcatT_kernel(const float* __restrict__ W1,
                                  unsigned short* __restrict__ WT) {
    int idx = blockIdx.x * 256 + threadIdx.x;
    if (idx >= 512 * 768) return;
    int n = idx / 768, k = idx - n * 768;
    float v = (n < 256) ? (W1[(size_t)k * 256 + n] - W1[(size_t)(k + 768) * 256 + n])
                        : W1[(size_t)(k + 768) * 256 + (n - 256)];
    WT[idx] = f2bf(v);
}

// ---- W2T[n][k] bf16 (256x256) ----------------------------------------------
__global__ void prep_w2T_kernel(const float* __restrict__ W2,
                                unsigned short* __restrict__ WT) {
    int idx = blockIdx.x * 256 + threadIdx.x;
    if (idx >= 256 * 256) return;
    int n = idx >> 8, k = idx & 255;
    WT[idx] = f2bf(W2[(size_t)k * 256 + n]);
}

// ------- RQ (N x 512 bf16) = hcat (N x 768 bf16) @ WcatT^T; R += b1 ---------
// MFMA 16x16x32 bf16. Block 256 thr / 4 waves; wave = 16-row strip x 64 cols.
__global__ __launch_bounds__(256)
void node_gemm_mfma_kernel(const unsigned short* __restrict__ A,
                           const unsigned short* __restrict__ BT,  // [512][768]
                           const float* __restrict__ b1,
                           unsigned short* __restrict__ C,
                           int M) {
    const int row0 = blockIdx.x * 64, col0 = blockIdx.y * 64;
    const int tid = threadIdx.x;
    const int wv = tid >> 6, lane = tid & 63;
    const int q = lane >> 4, nl = lane & 15;

    int row = row0 + wv * 16 + nl;
    int rowc = (row < M) ? row : (M - 1);
    const unsigned short* pa = A + (size_t)rowc * HC + q * 8;

    f32x4 acc[4];
#pragma unroll
    for (int t = 0; t < 4; ++t) acc[t] = (f32x4){0.f, 0.f, 0.f, 0.f};

    for (int ks = 0; ks < 24; ++ks) {
        const int k0 = ks * 32;
        const bf16x8 av = *(const bf16x8*)(pa + k0);
#pragma unroll
        for (int t = 0; t < 4; ++t) {
            const bf16x8 bv = *(const bf16x8*)(BT + (size_t)(col0 + t * 16 + nl) * 768 + k0 + q * 8);
            acc[t] = __builtin_amdgcn_mfma_f32_16x16x32_bf16(av, bv, acc[t], 0, 0, 0);
        }
    }

    const int r0 = row0 + wv * 16 + q * 4;
#pragma unroll
    for (int t = 0; t < 4; ++t) {
        int col = col0 + t * 16 + nl;
        float bb = (col < 256) ? b1[col] : 0.f;
#pragma unroll
        for (int i = 0; i < 4; ++i) {
            int r = r0 + i;
            if (r < M) C[(size_t)r * 512 + col] = f2bf(acc[t][i] + bb);
        }
    }
}

// ---------------- edge sort by dst: zero / hist / scan / scatter -------------
__global__ void zero_u32_kernel(unsigned* __restrict__ p, int count) {
    int idx = blockIdx.x * 256 + threadIdx.x;
    if (idx < count) p[idx] = 0u;
}
__global__ void hist_kernel(const int* __restrict__ dst, unsigned* __restrict__ cnt, int E) {
    int e = blockIdx.x * 256 + threadIdx.x;
    if (e < E) atomicAdd(&cnt[dst[e]], 1u);
}
__global__ void scan_kernel(const unsigned* __restrict__ cnt,
                            int* __restrict__ row_start, int N) {
    __shared__ unsigned buf[1024];
    __shared__ unsigned carry;
    const int tid = threadIdx.x;
    if (tid == 0) carry = 0u;
    __syncthreads();
    for (int base = 0; base < N; base += 1024) {
        int i = base + tid;
        unsigned v = (i < N) ? cnt[i] : 0u;
        buf[tid] = v;
        __syncthreads();
#pragma unroll
        for (int off = 1; off < 1024; off <<= 1) {
            unsigned add = (tid >= off) ? buf[tid - off] : 0u;
            __syncthreads();
            buf[tid] += add;
            __syncthreads();
        }
        if (i < N) row_start[i] = (int)(carry + buf[tid] - v);  // exclusive
        __syncthreads();
        if (tid == 0) carry += buf[1023];
        __syncthreads();
    }
    if (tid == 0) row_start[N] = (int)carry;  // == E
}
__global__ void scatter_kernel(const int* __restrict__ src, const int* __restrict__ dst,
                               const int* __restrict__ row_start,
                               unsigned* __restrict__ wcnt,
                               int* __restrict__ es, int* __restrict__ ed, int E) {
    int e = blockIdx.x * 256 + threadIdx.x;
    if (e >= E) return;
    int d = dst[e];
    int pos = row_start[d] + (int)atomicAdd(&wcnt[d], 1u);
    es[pos] = src[e];
    ed[pos] = d;
}

// ---- edges (layers 1,2), MFMA + dst-owner blocks ----------------------------
// relu(bf16(R[dst]) + bf16(Q[src])) @ W2 (bf16 MFMA, fp32 acc) -> seg-max in
// LDS -> relu(max + b2) stored bf16 straight into hcat. No global atomics.
__global__ __launch_bounds__(256)
void edge_mfma_kernel(const unsigned short* __restrict__ RQb,
                      const int* __restrict__ es,
                      const int* __restrict__ ed,
                      const int* __restrict__ row_start,   // N+1
                      const unsigned short* __restrict__ W2T,  // [256][256]
                      const float* __restrict__ b2,
                      unsigned short* __restrict__ hcat,
                      int N, int E) {
    __shared__ unsigned lseg[DPB * 256];
    __shared__ int ss[64], sdl[64];
    const int d0 = blockIdx.x * DPB;
    const int tid = threadIdx.x;
    const int wv = tid >> 6, lane = tid & 63;
    const int q = lane >> 4, nl = lane & 15;

    for (int i = tid; i < DPB * 256; i += 256) lseg[i] = ENC_NEG_INF;

    const int eBeg = row_start[d0];
    const int eEnd = row_start[min(d0 + DPB, N)];

    for (int c0 = eBeg; c0 < eEnd; c0 += 64) {
        __syncthreads();   // prior chunk done with ss/sdl; also covers lseg init
        if (tid < 64) {
            int e = c0 + tid;
            ss[tid]  = (e < eEnd) ? es[e] : 0;
            sdl[tid] = (e < eEnd) ? (ed[e] - d0) : -1;
        }
        __syncthreads();

        // A operand rows for this lane: edge = wv*16 + nl
        const int eloc = wv * 16 + nl;
        const int dln  = sdl[eloc];
        const int drow = (dln >= 0) ? (d0 + dln) : d0;
        const int srow = ss[eloc];
        const unsigned short* pd = RQb + (size_t)drow * 512 + q * 8;
        const unsigned short* ps = RQb + (size_t)srow * 512 + 256 + q * 8;

        f32x4 acc[16];
#pragma unroll
        for (int t = 0; t < 16; ++t) acc[t] = (f32x4){0.f, 0.f, 0.f, 0.f};

#pragma unroll
        for (int ks = 0; ks < 8; ++ks) {
            const int k0 = ks * 32;
            const bf16x8 dv = *(const bf16x8*)(pd + k0);
            const bf16x8 sv = *(const bf16x8*)(ps + k0);
            bf16x8 af;
#pragma unroll
            for (int j = 0; j < 8; ++j) {
                float fd = bf2f((unsigned short)dv[j]);
                float fs = bf2f((unsigned short)sv[j]);
                af[j] = (short)f2bf(fmaxf(fd + fs, 0.f));
            }
#pragma unroll
            for (int t = 0; t < 16; ++t) {
                const bf16x8 bv = *(const bf16x8*)(W2T + (size_t)(t * 16 + nl) * 256 + k0 + q * 8);
                acc[t] = __builtin_amdgcn_mfma_f32_16x16x32_bf16(af, bv, acc[t], 0, 0, 0);
            }
        }

        // epilogue: lane holds rows m = q*4+i of its wave's 16-edge tile,
        // col = t*16 + nl. Fold consecutive same-dst rows, LDS atomicMax.
        const int m0 = wv * 16 + q * 4;
        int dls[4];
#pragma unroll
        for (int i = 0; i < 4; ++i) dls[i] = sdl[m0 + i];
#pragma unroll
        for (int t = 0; t < 16; ++t) {
            const int col = t * 16 + nl;
            float cur = -INFINITY;
            int cd = dls[0];
#pragma unroll
            for (int i = 0; i < 4; ++i) {
                int dl = dls[i];
                if (dl != cd) {
                    if (cd >= 0) atomicMax(&lseg[cd * 256 + col], enc_f(cur));
                    cur = -INFINITY; cd = dl;
                }
                cur = fmaxf(cur, acc[t][i]);
            }
            if (cd >= 0) atomicMax(&lseg[cd * 256 + col], enc_f(cur));
        }
    }
    __syncthreads();

    // write relu(max + b2) (0 for empty segments) straight into hcat (bf16)
    for (int i = tid; i < DPB * 256; i += 256) {
        int dl = i >> 8, col = i & 255;
        int d = d0 + dl;
        if (d >= N) continue;
        float f = dec_f(lseg[i]);
        float v = isfinite(f) ? fmaxf(f + b2[col], 0.f) : 0.f;
        hcat[(size_t)d * HC + col] = f2bf(v);
    }
}

// ---- layer 3 edges: out width 3, one wave per edge --------------------------
__global__ void edge3_kernel(const unsigned short* __restrict__ RQb,
                             const int* __restrict__ src,
                             const int* __restrict__ dst,
                             const float* __restrict__ W2,   // 256x3
                             const float* __restrict__ b2,   // 3
                             unsigned* __restrict__ seg3,
                             int E) {
    int wave = blockIdx.x * 4 + (threadIdx.x >> 6);
    int lane = threadIdx.x & 63;
    if (wave >= E) return;
    int s = src[wave], d = dst[wave];
    float p0 = 0.f, p1 = 0.f, p2 = 0.f;
    for (int k = lane; k < 256; k += 64) {
        float a = fmaxf(bf2f(RQb[(size_t)d * 512 + k]) + bf2f(RQb[(size_t)s * 512 + 256 + k]), 0.f);
        p0 += a * W2[k * 3 + 0];
        p1 += a * W2[k * 3 + 1];
        p2 += a * W2[k * 3 + 2];
    }
#pragma unroll
    for (int off = 32; off > 0; off >>= 1) {
        p0 += __shfl_xor(p0, off);
        p1 += __shfl_xor(p1, off);
        p2 += __shfl_xor(p2, off);
    }
    if (lane == 0) {
        atomicMax(&seg3[(size_t)d * 3 + 0], enc_f(p0 + b2[0]));
        atomicMax(&seg3[(size_t)d * 3 + 1], enc_f(p1 + b2[1]));
        atomicMax(&seg3[(size_t)d * 3 + 2], enc_f(p2 + b2[2]));
    }
}

// ---------------- misc ------------------------------------------------------
__global__ void seg_init_kernel(unsigned* __restrict__ seg, int count) {
    int idx = blockIdx.x * 256 + threadIdx.x;
    if (idx < count) seg[idx] = ENC_NEG_INF;
}
__global__ void finalize3_kernel(const unsigned* __restrict__ seg3,
                                 const float* __restrict__ invstd,
                                 float* __restrict__ out, int N) {
    int idx = blockIdx.x * 256 + threadIdx.x;
    if (idx >= N * 3) return;
    int n = idx / 3;
    float f = dec_f(seg3[idx]);
    if (!isfinite(f)) f = 0.f;
    out[idx] = f * invstd[n];
}

extern "C" void kernel_launch(void* const* d_in, const int* in_sizes, int n_in,
                              void* d_out, int out_size, void* d_ws, size_t ws_size,
                              hipStream_t stream) {
    const float* x     = (const float*)d_in[0];
    const int*   ei    = (const int*)d_in[1];
    const float* t     = (const float*)d_in[2];
    const float* emb   = (const float*)d_in[3];
    const float* enc_W = (const float*)d_in[4];
    const float* enc_b = (const float*)d_in[5];
    const float* fw    = (const float*)d_in[6];
    const float* te_W  = (const float*)d_in[7];
    const float* te_b  = (const float*)d_in[8];
    const float* W1[3] = {(const float*)d_in[9],  (const float*)d_in[13], (const float*)d_in[17]};
    const float* b1[3] = {(const float*)d_in[10], (const float*)d_in[14], (const float*)d_in[18]};
    const float* W2[3] = {(const float*)d_in[11], (const float*)d_in[15], (const float*)d_in[19]};
    const float* b2[3] = {(const float*)d_in[12], (const float*)d_in[16], (const float*)d_in[20]};

    const int N = in_sizes[2];      // t is (N,1)
    const int E = in_sizes[1] / 2;  // edge_index is (2,E)
    const int* src = ei;
    const int* dst = ei + E;

    char* ws = (char*)d_ws;
    unsigned short* hcat  = (unsigned short*)ws; ws += (size_t)N * HC * 2;      // bf16
    unsigned short* RQb   = (unsigned short*)ws; ws += (size_t)N * 512 * 2;     // bf16
    unsigned short* WcatT = (unsigned short*)ws; ws += (size_t)512 * 768 * 2;   // bf16
    unsigned short* W2T   = (unsigned short*)ws; ws += (size_t)256 * 256 * 2;   // bf16
    unsigned* seg3        = (unsigned*)ws;       ws += (size_t)N * 3 * 4;
    float*    invstd      = (float*)ws;          ws += (size_t)N * 4;
    int*      es          = (int*)ws;            ws += (size_t)E * 4;
    int*      ed          = (int*)ws;            ws += (size_t)E * 4;
    unsigned* cnt         = (unsigned*)ws;       ws += (size_t)N * 4;
    unsigned* wcnt        = (unsigned*)ws;       ws += (size_t)N * 4;
    int*      row_start   = (int*)ws;            ws += (size_t)(N + 1) * 4;

    // ---- sort edges by dst (counting sort) ----
    zero_u32_kernel<<<(2 * N + 255) / 256, 256, 0, stream>>>(cnt, 2 * N); // cnt+wcnt adjacent
    hist_kernel<<<(E + 255) / 256, 256, 0, stream>>>(dst, cnt, E);
    scan_kernel<<<1, 1024, 0, stream>>>(cnt, row_start, N);
    scatter_kernel<<<(E + 255) / 256, 256, 0, stream>>>(src, dst, row_start, wcnt, es, ed, E);

    precompute_kernel<<<(N + 7) / 8, 256, 0, stream>>>(
        x, t, emb, enc_W, enc_b, fw, te_W, te_b, hcat, invstd, N);

    for (int l = 0; l < 3; ++l) {
        prep_wcatT_kernel<<<(512 * 768 + 255) / 256, 256, 0, stream>>>(W1[l], WcatT);
        dim3 gn((N + 63) / 64, 8);
        node_gemm_mfma_kernel<<<gn, 256, 0, stream>>>(hcat, WcatT, b1[l], RQb, N);
        if (l < 2) {
            prep_w2T_kernel<<<(256 * 256 + 255) / 256, 256, 0, stream>>>(W2[l], W2T);
            edge_mfma_kernel<<<(N + DPB - 1) / DPB, 256, 0, stream>>>(
                RQb, es, ed, row_start, W2T, b2[l], hcat, N, E);
        } else {
            seg_init_kernel<<<(N * 3 + 255) / 256, 256, 0, stream>>>(seg3, N * 3);
            edge3_kernel<<<(E + 3) / 4, 256, 0, stream>>>(RQb, es, ed, W2[l], b2[l], seg3, E);
            finalize3_kernel<<<(N * 3 + 255) / 256, 256, 0, stream>>>(seg3, invstd, (float*)d_out, N);
        }
    }
}

// Round 5
// 641.174 us; speedup vs baseline: 3.0131x; 1.6646x over previous
//
#include <hip/hip_runtime.h>
#include <hip/hip_bf16.h>
#include <math.h>

#define HC 768   // 3F concat width (bf16 elements)
#define DPB 8    // dsts owned per block in edge kernel

typedef __attribute__((ext_vector_type(8))) short bf16x8;  // 8 bf16 (4 VGPRs)
typedef __attribute__((ext_vector_type(4))) float f32x4;   // MFMA accumulator

__device__ __forceinline__ float bf2f(unsigned short h) {
    return __uint_as_float(((unsigned)h) << 16);
}
__device__ __forceinline__ unsigned short f2bf(float f) {   // round-to-nearest-even
    unsigned u = __float_as_uint(f);
    return (unsigned short)((u + 0x7fffu + ((u >> 16) & 1u)) >> 16);
}

// order-preserving float->uint encoding for max
__device__ __forceinline__ unsigned enc_f(float f) {
    unsigned u = __float_as_uint(f);
    return (u & 0x80000000u) ? ~u : (u | 0x80000000u);
}
__device__ __forceinline__ float dec_f(unsigned e) {
    unsigned u = (e & 0x80000000u) ? (e & 0x7FFFFFFFu) : ~e;
    return __uint_as_float(u);
}
#define ENC_NEG_INF 0x007FFFFFu  // enc(-inf)

// ---------------- precompute: temb (Fourier+silu), h0, hcat(bf16), invstd ----
__global__ void precompute_kernel(const float* __restrict__ x,
                                  const float* __restrict__ t,
                                  const float* __restrict__ emb,
                                  const float* __restrict__ enc_W,
                                  const float* __restrict__ enc_b,
                                  const float* __restrict__ fw,
                                  const float* __restrict__ te_W,
                                  const float* __restrict__ te_b,
                                  unsigned short* __restrict__ hcat,
                                  float* __restrict__ invstd,
                                  int N) {
    __shared__ float ti[8][256];
    __shared__ float tv[8];
    const int n0 = blockIdx.x * 8;
    const int tid = threadIdx.x;

    if (tid < 8) {
        int n = n0 + tid;
        float tt = (n < N) ? t[n] : 1.0f;
        tv[tid] = tt;
        const float ln_s = 3.2188758248682006f; // ln(25)
        float p = expf(2.0f * tt * ln_s);       // SIGMA^(2t)
        float sd = sqrtf((p - 1.0f) / (2.0f * ln_s));
        if (n < N) invstd[n] = 1.0f / (sd + 1e-7f);
    }
    __syncthreads();

    const float TWO_PI = 6.283185307179586f;
    for (int p = tid; p < 8 * 128; p += 256) {
        int n = p >> 7, j = p & 127;
        float pr = tv[n] * fw[j] * TWO_PI;
        ti[n][j]       = sinf(pr);
        ti[n][j + 128] = cosf(pr);
    }
    __syncthreads();

    const int j = tid;
    float acc[8];
#pragma unroll
    for (int n = 0; n < 8; ++n) acc[n] = 0.f;
    for (int k = 0; k < 256; ++k) {
        float w = te_W[k * 256 + j];
#pragma unroll
        for (int n = 0; n < 8; ++n) acc[n] += ti[n][k] * w;
    }
    float bj  = te_b[j];
    float ew0 = enc_W[0 * 256 + j], ew1 = enc_W[1 * 256 + j], ew2 = enc_W[2 * 256 + j];
    float ebj = enc_b[j];
    for (int n = 0; n < 8; ++n) {
        int node = n0 + n;
        if (node >= N) break;
        float v = acc[n] + bj;
        float temb = v / (1.0f + expf(-v));   // silu
        float h0 = x[node * 3 + 0] * ew0 + x[node * 3 + 1] * ew1 +
                   x[node * 3 + 2] * ew2 + ebj;
        hcat[(size_t)node * HC + j]       = f2bf(h0);
        hcat[(size_t)node * HC + 256 + j] = f2bf(temb);
        hcat[(size_t)node * HC + 512 + j] = f2bf(emb[node * 256 + j]);
    }
}

// ---- WcatT[n][k] bf16 (512x768) via LDS tile transpose ----------------------
// n<256: W1[k][n]-W1[k+768][n]; n>=256: W1[k+768][n-256]
__global__ void prep_wcatT_kernel(const float* __restrict__ W1,
                                  unsigned short* __restrict__ WT) {
    __shared__ float buf[64][65];
    const int k0 = blockIdx.x * 64;   // 12 blocks
    const int n0 = blockIdx.y * 64;   // 8 blocks
    const int tid = threadIdx.x;
    const int tx = tid & 63, ty = tid >> 6;
#pragma unroll
    for (int i = 0; i < 16; ++i) {
        int kl = ty + i * 4;          // local k row
        int k = k0 + kl;
        int n = n0 + tx;
        float v = (n < 256) ? (W1[(size_t)k * 256 + n] - W1[(size_t)(k + 768) * 256 + n])
                            : W1[(size_t)(k + 768) * 256 + (n - 256)];
        buf[kl][tx] = v;
    }
    __syncthreads();
#pragma unroll
    for (int i = 0; i < 16; ++i) {
        int nl = ty + i * 4;          // local n row (output row)
        WT[(size_t)(n0 + nl) * 768 + k0 + tx] = f2bf(buf[tx][nl]);
    }
}

// ---- W2T[n][k] bf16 (256x256) via LDS tile transpose ------------------------
__global__ void prep_w2T_kernel(const float* __restrict__ W2,
                                unsigned short* __restrict__ WT) {
    __shared__ float buf[64][65];
    const int k0 = blockIdx.x * 64;   // 4
    const int n0 = blockIdx.y * 64;   // 4
    const int tid = threadIdx.x;
    const int tx = tid & 63, ty = tid >> 6;
#pragma unroll
    for (int i = 0; i < 16; ++i) {
        int kl = ty + i * 4;
        buf[kl][tx] = W2[(size_t)(k0 + kl) * 256 + n0 + tx];
    }
    __syncthreads();
#pragma unroll
    for (int i = 0; i < 16; ++i) {
        int nl = ty + i * 4;
        WT[(size_t)(n0 + nl) * 256 + k0 + tx] = f2bf(buf[tx][nl]);
    }
}

// ------- RQ (N x 512 bf16) = hcat (N x 768 bf16) @ WcatT^T; R += b1 ---------
__global__ __launch_bounds__(256)
void node_gemm_mfma_kernel(const unsigned short* __restrict__ A,
                           const unsigned short* __restrict__ BT,  // [512][768]
                           const float* __restrict__ b1,
                           unsigned short* __restrict__ C,
                           int M) {
    const int row0 = blockIdx.x * 64, col0 = blockIdx.y * 64;
    const int tid = threadIdx.x;
    const int wv = tid >> 6, lane = tid & 63;
    const int q = lane >> 4, nl = lane & 15;

    int row = row0 + wv * 16 + nl;
    int rowc = (row < M) ? row : (M - 1);
    const unsigned short* pa = A + (size_t)rowc * HC + q * 8;

    f32x4 acc[4];
#pragma unroll
    for (int t = 0; t < 4; ++t) acc[t] = (f32x4){0.f, 0.f, 0.f, 0.f};

    for (int ks = 0; ks < 24; ++ks) {
        const int k0 = ks * 32;
        const bf16x8 av = *(const bf16x8*)(pa + k0);
#pragma unroll
        for (int t = 0; t < 4; ++t) {
            const bf16x8 bv = *(const bf16x8*)(BT + (size_t)(col0 + t * 16 + nl) * 768 + k0 + q * 8);
            acc[t] = __builtin_amdgcn_mfma_f32_16x16x32_bf16(av, bv, acc[t], 0, 0, 0);
        }
    }

    const int r0 = row0 + wv * 16 + q * 4;
#pragma unroll
    for (int t = 0; t < 4; ++t) {
        int col = col0 + t * 16 + nl;
        float bb = (col < 256) ? b1[col] : 0.f;
#pragma unroll
        for (int i = 0; i < 4; ++i) {
            int r = r0 + i;
            if (r < M) C[(size_t)r * 512 + col] = f2bf(acc[t][i] + bb);
        }
    }
}

// ---------------- edge sort by dst: zero / hist / scan / scatter -------------
__global__ void zero_u32_kernel(unsigned* __restrict__ p, int count) {
    int idx = blockIdx.x * 256 + threadIdx.x;
    if (idx < count) p[idx] = 0u;
}
__global__ void hist_kernel(const int* __restrict__ dst, unsigned* __restrict__ cnt, int E) {
    int e = blockIdx.x * 256 + threadIdx.x;
    if (e < E) atomicAdd(&cnt[dst[e]], 1u);
}
__global__ void scan_kernel(const unsigned* __restrict__ cnt,
                            int* __restrict__ row_start, int N) {
    __shared__ unsigned buf[1024];
    __shared__ unsigned carry;
    const int tid = threadIdx.x;
    if (tid == 0) carry = 0u;
    __syncthreads();
    for (int base = 0; base < N; base += 1024) {
        int i = base + tid;
        unsigned v = (i < N) ? cnt[i] : 0u;
        buf[tid] = v;
        __syncthreads();
#pragma unroll
        for (int off = 1; off < 1024; off <<= 1) {
            unsigned add = (tid >= off) ? buf[tid - off] : 0u;
            __syncthreads();
            buf[tid] += add;
            __syncthreads();
        }
        if (i < N) row_start[i] = (int)(carry + buf[tid] - v);  // exclusive
        __syncthreads();
        if (tid == 0) carry += buf[1023];
        __syncthreads();
    }
    if (tid == 0) row_start[N] = (int)carry;  // == E
}
__global__ void scatter_kernel(const int* __restrict__ src, const int* __restrict__ dst,
                               const int* __restrict__ row_start,
                               unsigned* __restrict__ wcnt,
                               int* __restrict__ es, int* __restrict__ ed, int E) {
    int e = blockIdx.x * 256 + threadIdx.x;
    if (e >= E) return;
    int d = dst[e];
    int pos = row_start[d] + (int)atomicAdd(&wcnt[d], 1u);
    es[pos] = src[e];
    ed[pos] = d;
}

// ---- edges (layers 1,2): LDS-staged AF + MFMA + dst-owner seg-max -----------
// Chunk of 64 sorted edges: stage af=relu(R[dst]+Q[src]) in LDS (repacked ONCE),
// wave w computes cols w*64..+63, one 16-edge subtile at a time (acc[4] only).
// Segment max -> LDS atomics; final relu(max+b2) stored bf16 into hcat.
__global__ __launch_bounds__(256, 3)
void edge_seg_gemm_kernel(const unsigned short* __restrict__ RQb,
                          const int* __restrict__ es,
                          const int* __restrict__ ed,
                          const int* __restrict__ row_start,   // N+1
                          const unsigned short* __restrict__ W2T,  // [256][256]
                          const float* __restrict__ b2,
                          unsigned short* __restrict__ hcat,
                          int N, int E) {
    __shared__ unsigned short af[64][264];   // padded: bank-uniform b128 r/w
    __shared__ unsigned lseg[DPB * 256];
    __shared__ int ss[64], sdl[64];
    const int d0 = blockIdx.x * DPB;
    const int tid = threadIdx.x;
    const int wv = tid >> 6, lane = tid & 63;
    const int q = lane >> 4, nl = lane & 15;

    for (int i = tid; i < DPB * 256; i += 256) lseg[i] = ENC_NEG_INF;

    const int eBeg = row_start[d0];
    const int eEnd = row_start[min(d0 + DPB, N)];

    for (int c0 = eBeg; c0 < eEnd; c0 += 64) {
        __syncthreads();   // prior chunk fully consumed af/sdl
        if (tid < 64) {
            int e = c0 + tid;
            ss[tid]  = (e < eEnd) ? es[e] : 0;
            sdl[tid] = (e < eEnd) ? (ed[e] - d0) : -1;
        }
        __syncthreads();

        // stage AF: 64 edges x 256 k; thread = (edge tid>>2, k-chunk (tid&3)*64)
        {
            const int el = tid >> 2;
            const int kc = (tid & 3) * 64;
            int dl = sdl[el];
            int drow = d0 + (dl >= 0 ? dl : 0);
            int srow = ss[el];
            const unsigned short* pd = RQb + (size_t)drow * 512 + kc;
            const unsigned short* ps = RQb + (size_t)srow * 512 + 256 + kc;
#pragma unroll
            for (int j = 0; j < 8; ++j) {
                bf16x8 dv = *(const bf16x8*)(pd + j * 8);
                bf16x8 sv = *(const bf16x8*)(ps + j * 8);
                bf16x8 a8;
#pragma unroll
                for (int u = 0; u < 8; ++u) {
                    float f = bf2f((unsigned short)dv[u]) + bf2f((unsigned short)sv[u]);
                    a8[u] = (short)f2bf(fmaxf(f, 0.f));
                }
                *(bf16x8*)&af[el][kc + j * 8] = a8;
            }
        }
        __syncthreads();

        // GEMM + segmented-max, one 16-edge subtile at a time
#pragma unroll
        for (int sub = 0; sub < 4; ++sub) {
            f32x4 acc[4];
#pragma unroll
            for (int t = 0; t < 4; ++t) acc[t] = (f32x4){0.f, 0.f, 0.f, 0.f};
#pragma unroll
            for (int ks = 0; ks < 8; ++ks) {
                const bf16x8 av = *(const bf16x8*)&af[sub * 16 + nl][ks * 32 + q * 8];
#pragma unroll
                for (int t = 0; t < 4; ++t) {
                    const bf16x8 bv = *(const bf16x8*)(W2T +
                        (size_t)(wv * 64 + t * 16 + nl) * 256 + ks * 32 + q * 8);
                    acc[t] = __builtin_amdgcn_mfma_f32_16x16x32_bf16(av, bv, acc[t], 0, 0, 0);
                }
            }
            // epilogue: lane holds rows m = sub*16 + q*4 + i, col = wv*64+t*16+nl
            const int m0 = sub * 16 + q * 4;
            int dls[4];
#pragma unroll
            for (int i = 0; i < 4; ++i) dls[i] = sdl[m0 + i];
#pragma unroll
            for (int t = 0; t < 4; ++t) {
                const int col = wv * 64 + t * 16 + nl;
                float cur = -INFINITY;
                int cd = dls[0];
#pragma unroll
                for (int i = 0; i < 4; ++i) {
                    int dl = dls[i];
                    if (dl != cd) {
                        if (cd >= 0) atomicMax(&lseg[cd * 256 + col], enc_f(cur));
                        cur = -INFINITY; cd = dl;
                    }
                    cur = fmaxf(cur, acc[t][i]);
                }
                if (cd >= 0) atomicMax(&lseg[cd * 256 + col], enc_f(cur));
            }
        }
    }
    __syncthreads();

    // write relu(max + b2) (0 for empty segments) straight into hcat (bf16)
    for (int i = tid; i < DPB * 256; i += 256) {
        int dl = i >> 8, col = i & 255;
        int d = d0 + dl;
        if (d >= N) continue;
        float f = dec_f(lseg[i]);
        float v = isfinite(f) ? fmaxf(f + b2[col], 0.f) : 0.f;
        hcat[(size_t)d * HC + col] = f2bf(v);
    }
}

// ---- layer 3 edges: out width 3, one wave per edge --------------------------
__global__ void edge3_kernel(const unsigned short* __restrict__ RQb,
                             const int* __restrict__ src,
                             const int* __restrict__ dst,
                             const float* __restrict__ W2,   // 256x3
                             const float* __restrict__ b2,   // 3
                             unsigned* __restrict__ seg3,
                             int E) {
    int wave = blockIdx.x * 4 + (threadIdx.x >> 6);
    int lane = threadIdx.x & 63;
    if (wave >= E) return;
    int s = src[wave], d = dst[wave];
    float p0 = 0.f, p1 = 0.f, p2 = 0.f;
    for (int k = lane; k < 256; k += 64) {
        float a = fmaxf(bf2f(RQb[(size_t)d * 512 + k]) + bf2f(RQb[(size_t)s * 512 + 256 + k]), 0.f);
        p0 += a * W2[k * 3 + 0];
        p1 += a * W2[k * 3 + 1];
        p2 += a * W2[k * 3 + 2];
    }
#pragma unroll
    for (int off = 32; off > 0; off >>= 1) {
        p0 += __shfl_xor(p0, off);
        p1 += __shfl_xor(p1, off);
        p2 += __shfl_xor(p2, off);
    }
    if (lane == 0) {
        atomicMax(&seg3[(size_t)d * 3 + 0], enc_f(p0 + b2[0]));
        atomicMax(&seg3[(size_t)d * 3 + 1], enc_f(p1 + b2[1]));
        atomicMax(&seg3[(size_t)d * 3 + 2], enc_f(p2 + b2[2]));
    }
}

// ---------------- misc ------------------------------------------------------
__global__ void seg_init_kernel(unsigned* __restrict__ seg, int count) {
    int idx = blockIdx.x * 256 + threadIdx.x;
    if (idx < count) seg[idx] = ENC_NEG_INF;
}
__global__ void finalize3_kernel(const unsigned* __restrict__ seg3,
                                 const float* __restrict__ invstd,
                                 float* __restrict__ out, int N) {
    int idx = blockIdx.x * 256 + threadIdx.x;
    if (idx >= N * 3) return;
    int n = idx / 3;
    float f = dec_f(seg3[idx]);
    if (!isfinite(f)) f = 0.f;
    out[idx] = f * invstd[n];
}

extern "C" void kernel_launch(void* const* d_in, const int* in_sizes, int n_in,
                              void* d_out, int out_size, void* d_ws, size_t ws_size,
                              hipStream_t stream) {
    const float* x     = (const float*)d_in[0];
    const int*   ei    = (const int*)d_in[1];
    const float* t     = (const float*)d_in[2];
    const float* emb   = (const float*)d_in[3];
    const float* enc_W = (const float*)d_in[4];
    const float* enc_b = (const float*)d_in[5];
    const float* fw    = (const float*)d_in[6];
    const float* te_W  = (const float*)d_in[7];
    const float* te_b  = (const float*)d_in[8];
    const float* W1[3] = {(const float*)d_in[9],  (const float*)d_in[13], (const float*)d_in[17]};
    const float* b1[3] = {(const float*)d_in[10], (const float*)d_in[14], (const float*)d_in[18]};
    const float* W2[3] = {(const float*)d_in[11], (const float*)d_in[15], (const float*)d_in[19]};
    const float* b2[3] = {(const float*)d_in[12], (const float*)d_in[16], (const float*)d_in[20]};

    const int N = in_sizes[2];      // t is (N,1)
    const int E = in_sizes[1] / 2;  // edge_index is (2,E)
    const int* src = ei;
    const int* dst = ei + E;

    char* ws = (char*)d_ws;
    unsigned short* hcat  = (unsigned short*)ws; ws += (size_t)N * HC * 2;      // bf16
    unsigned short* RQb   = (unsigned short*)ws; ws += (size_t)N * 512 * 2;     // bf16
    unsigned short* WcatT = (unsigned short*)ws; ws += (size_t)512 * 768 * 2;   // bf16
    unsigned short* W2T   = (unsigned short*)ws; ws += (size_t)256 * 256 * 2;   // bf16
    unsigned* seg3        = (unsigned*)ws;       ws += (size_t)N * 3 * 4;
    float*    invstd      = (float*)ws;          ws += (size_t)N * 4;
    int*      es          = (int*)ws;            ws += (size_t)E * 4;
    int*      ed          = (int*)ws;            ws += (size_t)E * 4;
    unsigned* cnt         = (unsigned*)ws;       ws += (size_t)N * 4;
    unsigned* wcnt        = (unsigned*)ws;       ws += (size_t)N * 4;
    int*      row_start   = (int*)ws;            ws += (size_t)(N + 1) * 4;

    // ---- sort edges by dst (counting sort) ----
    zero_u32_kernel<<<(2 * N + 255) / 256, 256, 0, stream>>>(cnt, 2 * N); // cnt+wcnt adjacent
    hist_kernel<<<(E + 255) / 256, 256, 0, stream>>>(dst, cnt, E);
    scan_kernel<<<1, 1024, 0, stream>>>(cnt, row_start, N);
    scatter_kernel<<<(E + 255) / 256, 256, 0, stream>>>(src, dst, row_start, wcnt, es, ed, E);

    precompute_kernel<<<(N + 7) / 8, 256, 0, stream>>>(
        x, t, emb, enc_W, enc_b, fw, te_W, te_b, hcat, invstd, N);

    for (int l = 0; l < 3; ++l) {
        dim3 gw(12, 8);
        prep_wcatT_kernel<<<gw, 256, 0, stream>>>(W1[l], WcatT);
        dim3 gn((N + 63) / 64, 8);
        node_gemm_mfma_kernel<<<gn, 256, 0, stream>>>(hcat, WcatT, b1[l], RQb, N);
        if (l < 2) {
            dim3 g2(4, 4);
            prep_w2T_kernel<<<g2, 256, 0, stream>>>(W2[l], W2T);
            edge_seg_gemm_kernel<<<(N + DPB - 1) / DPB, 256, 0, stream>>>(
                RQb, es, ed, row_start, W2T, b2[l], hcat, N, E);
        } else {
            seg_init_kernel<<<(N * 3 + 255) / 256, 256, 0, stream>>>(seg3, N * 3);
            edge3_kernel<<<(E + 3) / 4, 256, 0, stream>>>(RQb, es, ed, W2[l], b2[l], seg3, E);
            finalize3_kernel<<<(N * 3 + 255) / 256, 256, 0, stream>>>(seg3, invstd, (float*)d_out, N);
        }
    }
}